// Round 6
// baseline (247.631 us; speedup 1.0000x reference)
//
#include <hip/hip_runtime.h>
#include <hip/hip_cooperative_groups.h>

namespace cg = cooperative_groups;

// Problem constants
#define Bz 16      // batch
#define Tin 12     // T_IN
#define Ttot 24    // T_TOTAL
#define NN 5000    // nodes
#define KK 16      // neighbors
#define HH 4       // heads
#define OO 12      // T_TOTAL - T_IN
#define TH 48      // Tin * HH
#define G  8       // bt-groups (2 batches each) == number of XCDs
#define JJ 24      // (b,t) pairs per group

// Fused-kernel geometry — SAFE occupancy margins (4 blocks/CU, grid 1024)
#define BPG 128    // blocks per group; grid = 8 * 128 = 1024 = 256 CUs * 4
#define NPB 8      // nodes per node-group (625 groups per g)
#define GPG 625
#define TNB 40     // transpose tile: nodes per tile; 125 * 40 = 5000 exact
#define NT  125

// feat LDS strides (float4 units)
#define FST 5      // per-t   (4 heads + 1 pad)
#define FSB 61     // per-b_l (12*5 + 1)
#define FSN 122    // per-nl  (2*61)

// smem layout (bytes): region A (tile 24x41 f4 = 15744 | feat 976 f4 = 15616)
// then w4_s, nbr_s, W_s, bias_s
#define OFF_W4   16000
#define OFF_NBR  18048
#define OFF_WS   18560
#define OFF_BIAS 20864
#define SMEM_BYTES 20928

typedef float f32x4 __attribute__((ext_vector_type(4)));
__device__ __forceinline__ void nt_store4(float4* p, float4 v) {
    f32x4 t; t.x = v.x; t.y = v.y; t.z = v.z; t.w = v.w;
    __builtin_nontemporal_store(t, (f32x4*)p);
}

__global__ __launch_bounds__(256, 4) void gnn_fused_kernel(
    const float4* __restrict__ x4,    // (BT, N)
    float4* __restrict__ xT2,         // (G, N, JJ)
    const float* __restrict__ dists,  // (N, K)
    const float* __restrict__ W,      // (48, 12)
    const float* __restrict__ bias,   // (12,)
    const int*   __restrict__ nbrs,   // (N, K)
    float4* __restrict__ out4)        // (B*Ttot, N)
{
    __shared__ __align__(16) unsigned char smem[SMEM_BYTES];
    float4* feat   = (float4*)smem;
    float4 (*tile)[TNB + 1] = (float4(*)[TNB + 1])smem;   // [24][41]
    float4* w4_s   = (float4*)(smem + OFF_W4);            // [8][16]
    int*    nbr_s  = (int*)  (smem + OFF_NBR);            // [8][16]
    float*  W_s    = (float*)(smem + OFF_WS);             // 576
    float*  bias_s = (float*)(smem + OFF_BIAS);           // 12

    const int bid  = blockIdx.x;
    const int g    = bid & 7;          // XCD-pin (locality heuristic only)
    const int bidg = bid >> 3;         // 0..127 within group
    const int tid  = threadIdx.x;

    // ============ phase T: concat-copy (all blocks) + transpose ============
    for (int idx = bidg * 256 + tid; idx < JJ * NN; idx += BPG * 256) {
        int j  = idx / NN;
        int n  = idx - j * NN;
        int bt = g * JJ + j;
        int b  = bt / Tin, t = bt - b * Tin;
        float4 v = x4[(size_t)bt * NN + n];
        nt_store4(&out4[(size_t)(b * Ttot + t) * NN + n], v);
    }
    if (bidg < NT) {
        const int n0 = bidg * TNB;
        for (int tau = tid; tau < TNB * JJ; tau += 256) {
            int jj = tau / TNB;                 // 0..23
            int ii = tau % TNB;                 // node (lane-consecutive)
            tile[jj][ii] = x4[(size_t)(g * JJ + jj) * NN + n0 + ii];
        }
        __syncthreads();
        for (int tau = tid; tau < TNB * JJ; tau += 256) {
            int i = tau / JJ;                   // node
            int j = tau % JJ;                   // j (lane-consecutive, 384 B/node)
            xT2[((size_t)g * NN + n0 + i) * JJ + j] = tile[j][i];
        }
    }

    cg::this_grid().sync();

    // ============ phase M: gather + aggregate + GEMM + ReLU ================
    for (int i = tid; i < TH * OO; i += 256) W_s[i] = W[i];
    if (tid < OO) bias_s[tid] = bias[tid];

    const float4* xg = xT2 + (size_t)g * NN * JJ;

    for (int grp = bidg; grp < GPG; grp += BPG) {
        const int n0 = grp * NPB;

        if (tid < NPB * KK) {
            int nl = tid >> 4, k = tid & 15;
            nbr_s[nl * KK + k] = nbrs[(n0 + nl) * KK + k];
            float d = dists[(n0 + nl) * KK + k];
            float e = -(d * d) * (1.0f / 144.0f);   // h=0 exponent (lam=1/4)
            float4 wv;
            wv.x = expf(e);
            wv.y = expf(2.0f * e);
            wv.z = expf(3.0f * e);
            wv.w = expf(4.0f * e);
            w4_s[nl * KK + k] = wv;
        }
        __syncthreads();   // staging done; also protects feat vs prev GEMM reads

        if (tid < NPB * JJ) {
            const int nl  = tid / JJ;              // 0..7
            const int j   = tid - nl * JJ;         // 0..23 (lane-consecutive)
            const int b_l = j / Tin;
            const int t   = j - b_l * Tin;
            float4 a0 = {0,0,0,0}, a1 = {0,0,0,0}, a2 = {0,0,0,0}, a3 = {0,0,0,0};
            #pragma unroll
            for (int k = 0; k < KK; k++) {
                float4 xv = xg[(size_t)nbr_s[nl * KK + k] * JJ + j];
                float4 wv = w4_s[nl * KK + k];
                a0.x += wv.x * xv.x; a0.y += wv.x * xv.y; a0.z += wv.x * xv.z; a0.w += wv.x * xv.w;
                a1.x += wv.y * xv.x; a1.y += wv.y * xv.y; a1.z += wv.y * xv.z; a1.w += wv.y * xv.w;
                a2.x += wv.z * xv.x; a2.y += wv.z * xv.y; a2.z += wv.z * xv.z; a2.w += wv.z * xv.w;
                a3.x += wv.w * xv.x; a3.y += wv.w * xv.y; a3.z += wv.w * xv.z; a3.w += wv.w * xv.w;
            }
            const int base = nl * FSN + b_l * FSB + t * FST;
            feat[base + 0] = a0;
            feat[base + 1] = a1;
            feat[base + 2] = a2;
            feat[base + 3] = a3;
        }
        __syncthreads();

        if (tid < NPB * JJ) {
            const int nl  = tid & 7;               // lane-consecutive -> 128 B
            const int bo  = tid >> 3;              // 0..23
            const int b_l = bo / OO;
            const int o   = bo - b_l * OO;
            const float bz = bias_s[o];
            float4 acc = {bz, bz, bz, bz};
            const int fbase = nl * FSN + b_l * FSB;
            #pragma unroll
            for (int t = 0; t < Tin; t++) {
                #pragma unroll
                for (int h = 0; h < HH; h++) {
                    float  wv = W_s[(t * HH + h) * OO + o];
                    float4 f  = feat[fbase + t * FST + h];
                    acc.x += wv * f.x; acc.y += wv * f.y;
                    acc.z += wv * f.z; acc.w += wv * f.w;
                }
            }
            acc.x = fmaxf(acc.x, 0.0f); acc.y = fmaxf(acc.y, 0.0f);
            acc.z = fmaxf(acc.z, 0.0f); acc.w = fmaxf(acc.w, 0.0f);
            const int b = g * 2 + b_l;
            nt_store4(&out4[(size_t)(b * Ttot + Tin + o) * NN + n0 + nl], acc);
        }
    }
}

// ================= fallback: known-good R4 two-kernel path ==================
#define K1_NB 64

__global__ __launch_bounds__(256) void transpose_kernel(
    const float4* __restrict__ x4, float4* __restrict__ xT2)
{
    __shared__ float4 tileA[JJ][K1_NB + 1];
    const int bid = blockIdx.x;
    const int g   = bid & 7;
    const int n0  = (bid >> 3) * K1_NB;
    const int rem = min(K1_NB, NN - n0);
    const int tid = threadIdx.x;
    #pragma unroll
    for (int r = 0; r < (K1_NB * JJ) / 256; r++) {
        int tau = r * 256 + tid;
        int j = tau / K1_NB, i = tau % K1_NB;
        if (i < rem)
            tileA[j][i] = x4[(size_t)(g * JJ + j) * NN + n0 + i];
    }
    __syncthreads();
    #pragma unroll
    for (int r = 0; r < (K1_NB * JJ) / 256; r++) {
        int tau = r * 256 + tid;
        int i = tau / JJ, j = tau - i * JJ;
        if (i < rem)
            xT2[((size_t)g * NN + n0 + i) * JJ + j] = tileA[j][i];
    }
}

__global__ __launch_bounds__(192) void gnn_main_kernel(
    const float4* __restrict__ x4, const float4* __restrict__ xT2,
    const float* __restrict__ dists, const float* __restrict__ W,
    const float* __restrict__ bias, const int* __restrict__ nbrs,
    float4* __restrict__ out4)
{
    __shared__ float4 featB[NPB * 123];
    __shared__ float4 w4B[NPB][KK];
    __shared__ float  WB[TH * OO];
    __shared__ float  biasB[OO];
    __shared__ int    nbrB[NPB][KK];
    const int bid = blockIdx.x;
    const int g   = bid & 7;
    const int n0  = (bid >> 3) * NPB;
    const int tid = threadIdx.x;
    for (int i = tid; i < TH * OO; i += 192) WB[i] = W[i];
    if (tid < OO) biasB[tid] = bias[tid];
    if (tid < NPB * KK) {
        int nl = tid >> 4, k = tid & 15;
        nbrB[nl][k] = nbrs[(n0 + nl) * KK + k];
        float d = dists[(n0 + nl) * KK + k];
        float e = -(d * d) * (1.0f / 144.0f);
        float4 wv;
        wv.x = expf(e); wv.y = expf(2.0f * e);
        wv.z = expf(3.0f * e); wv.w = expf(4.0f * e);
        w4B[nl][k] = wv;
    }
    {
        const int j  = tid >> 3;
        const int nl = tid & 7;
        const int bt = g * JJ + j;
        const int b  = bt / Tin, t = bt - b * Tin;
        float4 v = x4[(size_t)bt * NN + n0 + nl];
        nt_store4(&out4[(size_t)(b * Ttot + t) * NN + n0 + nl], v);
    }
    __syncthreads();
    {
        const int nl  = tid / JJ;
        const int j   = tid - nl * JJ;
        const int b_l = j / Tin;
        const int t   = j - b_l * Tin;
        const float4* xg = xT2 + (size_t)g * NN * JJ;
        float4 a0 = {0,0,0,0}, a1 = {0,0,0,0}, a2 = {0,0,0,0}, a3 = {0,0,0,0};
        #pragma unroll
        for (int k = 0; k < KK; k++) {
            float4 xv = xg[(size_t)nbrB[nl][k] * JJ + j];
            float4 wv = w4B[nl][k];
            a0.x += wv.x * xv.x; a0.y += wv.x * xv.y; a0.z += wv.x * xv.z; a0.w += wv.x * xv.w;
            a1.x += wv.y * xv.x; a1.y += wv.y * xv.y; a1.z += wv.y * xv.z; a1.w += wv.y * xv.w;
            a2.x += wv.z * xv.x; a2.y += wv.z * xv.y; a2.z += wv.z * xv.z; a2.w += wv.z * xv.w;
            a3.x += wv.w * xv.x; a3.y += wv.w * xv.y; a3.z += wv.w * xv.z; a3.w += wv.w * xv.w;
        }
        const int base = nl * 123 + b_l * FSB + t * FST;
        featB[base + 0] = a0; featB[base + 1] = a1;
        featB[base + 2] = a2; featB[base + 3] = a3;
    }
    __syncthreads();
    {
        const int nl  = tid & 7;
        const int bo  = tid >> 3;
        const int b_l = bo / OO;
        const int o   = bo - b_l * OO;
        const float bz = biasB[o];
        float4 acc = {bz, bz, bz, bz};
        const int fbase = nl * 123 + b_l * FSB;
        #pragma unroll
        for (int t = 0; t < Tin; t++)
            #pragma unroll
            for (int h = 0; h < HH; h++) {
                float  wv = WB[(t * HH + h) * OO + o];
                float4 f  = featB[fbase + t * FST + h];
                acc.x += wv * f.x; acc.y += wv * f.y;
                acc.z += wv * f.z; acc.w += wv * f.w;
            }
        acc.x = fmaxf(acc.x, 0.0f); acc.y = fmaxf(acc.y, 0.0f);
        acc.z = fmaxf(acc.z, 0.0f); acc.w = fmaxf(acc.w, 0.0f);
        const int b = g * 2 + b_l;
        nt_store4(&out4[(size_t)(b * Ttot + Tin + o) * NN + n0 + nl], acc);
    }
}

extern "C" void kernel_launch(void* const* d_in, const int* in_sizes, int n_in,
                              void* d_out, int out_size, void* d_ws, size_t ws_size,
                              hipStream_t stream) {
    const float4* x4    = (const float4*)d_in[0];
    const float*  dists = (const float*)d_in[1];
    const float*  W     = (const float*)d_in[2];
    const float*  bias  = (const float*)d_in[3];
    const int*    nbrs  = (const int*)d_in[4];
    float4* out4 = (float4*)d_out;
    float4* xT2  = (float4*)d_ws;     // G*NN*JJ*16 B = 15.36 MB of ws

    void* args[] = { (void*)&x4, (void*)&xT2, (void*)&dists, (void*)&W,
                     (void*)&bias, (void*)&nbrs, (void*)&out4 };
    hipError_t err = hipLaunchCooperativeKernel(
        (const void*)gnn_fused_kernel, dim3(G * BPG), dim3(256),
        args, 0, stream);

    if (err != hipSuccess) {
        // deterministic fallback: known-good two-kernel path
        const int ntiles = (NN + K1_NB - 1) / K1_NB;   // 79
        hipLaunchKernelGGL(transpose_kernel, dim3(ntiles * G), dim3(256), 0,
                           stream, x4, xT2);
        hipLaunchKernelGGL(gnn_main_kernel, dim3((NN / NPB) * G), dim3(192), 0,
                           stream, x4, (const float4*)xT2,
                           dists, W, bias, nbrs, out4);
    }
}

// Round 7
// 207.808 us; speedup vs baseline: 1.1916x; 1.1916x over previous
//
#include <hip/hip_runtime.h>

// Problem constants
#define Bz 16      // batch
#define Tin 12     // T_IN
#define Ttot 24    // T_TOTAL
#define NN 5000    // nodes
#define KK 16      // neighbors
#define HH 4       // heads
#define OO 12      // T_TOTAL - T_IN
#define TH 48      // Tin * HH
#define G  8       // bt-groups (2 batches each) == number of XCDs
#define JJ 24      // (b,t) pairs per group

// Geometry — grid 768 = 3 blocks/CU guaranteed co-resident:
//   LDS 29.9 KB -> <=5/CU; waves 4/block -> <=8/CU; VGPR ~60 -> no limit.
#define BPG 96     // blocks per group; grid = 8 * 96 = 768
#define GRID (G * BPG)
#define NPB 8      // nodes per node-group
#define GPG 625    // node-groups per g (5000/8)
#define TNB 64     // transpose tile nodes; 79 tiles covers 5000 (last rem=8)
#define NT  79

// feat LDS strides (float4 units)
#define FST 5      // per-t   (4 heads + 1 pad)
#define FSB 61     // per-b_l (12*5 + 1)
#define FSN 122    // per-nl  (2*61)

// smem: region A = union(tile[24][65] f4 = 24960 B, feat 976 f4 = 15616 B)
#define OFF_W4   24960
#define OFF_NBR  27008
#define OFF_WS   27520
#define OFF_BIAS 29824
#define SMEM_BYTES 29888

typedef float f32x4 __attribute__((ext_vector_type(4)));
__device__ __forceinline__ void nt_store4(float4* p, float4 v) {
    f32x4 t; t.x = v.x; t.y = v.y; t.z = v.z; t.w = v.w;
    __builtin_nontemporal_store(t, (f32x4*)p);
}

__global__ __launch_bounds__(256, 3) void gnn_fused_kernel(
    const float4* __restrict__ x4,    // (BT, N)
    float4* __restrict__ xT2,         // (G, N, JJ) in d_ws
    unsigned* __restrict__ barrier_ctr, // in d_ws, poisoned to 0xAAAAAAAA
    const float* __restrict__ dists,  // (N, K)
    const float* __restrict__ W,      // (48, 12)
    const float* __restrict__ bias,   // (12,)
    const int*   __restrict__ nbrs,   // (N, K)
    float4* __restrict__ out4)        // (B*Ttot, N)
{
    __shared__ __align__(16) unsigned char smem[SMEM_BYTES];
    float4* feat   = (float4*)smem;
    float4 (*tile)[TNB + 1] = (float4(*)[TNB + 1])smem;   // [24][65]
    float4* w4_s   = (float4*)(smem + OFF_W4);            // [8][16]
    int*    nbr_s  = (int*)  (smem + OFF_NBR);            // [8][16]
    float*  W_s    = (float*)(smem + OFF_WS);             // 576
    float*  bias_s = (float*)(smem + OFF_BIAS);           // 12

    const int bid  = blockIdx.x;
    const int g    = bid & 7;          // XCD-pin heuristic (locality only;
                                       // correctness covered by fences)
    const int bidg = bid >> 3;         // 0..95 within group
    const int tid  = threadIdx.x;

    // ============ phase T: concat-copy (all blocks) + transpose ============
    for (int idx = bidg * 256 + tid; idx < JJ * NN; idx += BPG * 256) {
        int j  = idx / NN;
        int n  = idx - j * NN;
        int bt = g * JJ + j;
        int b  = bt / Tin, t = bt - b * Tin;
        float4 v = x4[(size_t)bt * NN + n];
        nt_store4(&out4[(size_t)(b * Ttot + t) * NN + n], v);
    }
    if (bidg < NT) {
        const int n0  = bidg * TNB;
        const int rem = min(TNB, NN - n0);
        for (int tau = tid; tau < TNB * JJ; tau += 256) {
            int jj = tau / TNB;                 // 0..23
            int ii = tau % TNB;                 // node (lane-consecutive)
            if (ii < rem)
                tile[jj][ii] = x4[(size_t)(g * JJ + jj) * NN + n0 + ii];
        }
        __syncthreads();
        for (int tau = tid; tau < TNB * JJ; tau += 256) {
            int i = tau / JJ;                   // node
            int j = tau % JJ;                   // j (lane-consecutive)
            if (i < rem)
                xT2[((size_t)g * NN + n0 + i) * JJ + j] = tile[j][i];
        }
    }

    // ============ hand-rolled device-scope grid barrier ====================
    __syncthreads();                   // drain this block's memory ops
    if (tid == 0) {
        __threadfence();               // release: xT2 visible device-wide
        atomicAdd(barrier_ctr, 1u);    // device-scope by default
        const unsigned target = 0xAAAAAAAAu + (unsigned)GRID;  // poison-aware
        long iters = 0;
        while (__hip_atomic_load(barrier_ctr, __ATOMIC_RELAXED,
                                 __HIP_MEMORY_SCOPE_AGENT) < target) {
            __builtin_amdgcn_s_sleep(2);
            if (++iters > 50000000L) break;   // safety valve: fail visibly, not hang
        }
        __threadfence();               // acquire: invalidate stale lines
    }
    __syncthreads();

    // ============ phase M: gather + aggregate + GEMM + ReLU ================
    for (int i = tid; i < TH * OO; i += 256) W_s[i] = W[i];
    if (tid < OO) bias_s[tid] = bias[tid];

    const float4* xg = xT2 + (size_t)g * NN * JJ;

    for (int grp = bidg; grp < GPG; grp += BPG) {
        const int n0 = grp * NPB;

        if (tid < NPB * KK) {
            int nl = tid >> 4, k = tid & 15;
            nbr_s[nl * KK + k] = nbrs[(n0 + nl) * KK + k];
            float d = dists[(n0 + nl) * KK + k];
            float e = -(d * d) * (1.0f / 144.0f);   // h=0 exponent (lam=1/4)
            float4 wv;
            wv.x = expf(e);
            wv.y = expf(2.0f * e);
            wv.z = expf(3.0f * e);
            wv.w = expf(4.0f * e);
            w4_s[nl * KK + k] = wv;
        }
        __syncthreads();   // staging done; also protects feat vs prev GEMM reads

        if (tid < NPB * JJ) {
            const int nl  = tid / JJ;              // 0..7
            const int j   = tid - nl * JJ;         // 0..23 (lane-consecutive)
            const int b_l = j / Tin;
            const int t   = j - b_l * Tin;
            float4 a0 = {0,0,0,0}, a1 = {0,0,0,0}, a2 = {0,0,0,0}, a3 = {0,0,0,0};
            #pragma unroll
            for (int k = 0; k < KK; k++) {
                float4 xv = xg[(size_t)nbr_s[nl * KK + k] * JJ + j];
                float4 wv = w4_s[nl * KK + k];
                a0.x += wv.x * xv.x; a0.y += wv.x * xv.y; a0.z += wv.x * xv.z; a0.w += wv.x * xv.w;
                a1.x += wv.y * xv.x; a1.y += wv.y * xv.y; a1.z += wv.y * xv.z; a1.w += wv.y * xv.w;
                a2.x += wv.z * xv.x; a2.y += wv.z * xv.y; a2.z += wv.z * xv.z; a2.w += wv.z * xv.w;
                a3.x += wv.w * xv.x; a3.y += wv.w * xv.y; a3.z += wv.w * xv.z; a3.w += wv.w * xv.w;
            }
            const int base = nl * FSN + b_l * FSB + t * FST;
            feat[base + 0] = a0;
            feat[base + 1] = a1;
            feat[base + 2] = a2;
            feat[base + 3] = a3;
        }
        __syncthreads();

        if (tid < NPB * JJ) {
            const int nl  = tid & 7;               // lane-consecutive -> 128 B
            const int bo  = tid >> 3;              // 0..23
            const int b_l = bo / OO;
            const int o   = bo - b_l * OO;
            const float bz = bias_s[o];
            float4 acc = {bz, bz, bz, bz};
            const int fbase = nl * FSN + b_l * FSB;
            #pragma unroll
            for (int t = 0; t < Tin; t++) {
                #pragma unroll
                for (int h = 0; h < HH; h++) {
                    float  wv = W_s[(t * HH + h) * OO + o];
                    float4 f  = feat[fbase + t * FST + h];
                    acc.x += wv * f.x; acc.y += wv * f.y;
                    acc.z += wv * f.z; acc.w += wv * f.w;
                }
            }
            acc.x = fmaxf(acc.x, 0.0f); acc.y = fmaxf(acc.y, 0.0f);
            acc.z = fmaxf(acc.z, 0.0f); acc.w = fmaxf(acc.w, 0.0f);
            const int b = g * 2 + b_l;
            nt_store4(&out4[(size_t)(b * Ttot + Tin + o) * NN + n0 + nl], acc);
        }
    }
}

extern "C" void kernel_launch(void* const* d_in, const int* in_sizes, int n_in,
                              void* d_out, int out_size, void* d_ws, size_t ws_size,
                              hipStream_t stream) {
    const float4* x4    = (const float4*)d_in[0];
    const float*  dists = (const float*)d_in[1];
    const float*  W     = (const float*)d_in[2];
    const float*  bias  = (const float*)d_in[3];
    const int*    nbrs  = (const int*)d_in[4];
    float4*   out4 = (float4*)d_out;
    float4*   xT2  = (float4*)d_ws;                      // 15,360,000 B
    unsigned* ctr  = (unsigned*)((char*)d_ws + 15360000); // poisoned 0xAAAAAAAA

    hipLaunchKernelGGL(gnn_fused_kernel, dim3(GRID), dim3(256), 0, stream,
                       x4, xT2, ctr, dists, W, bias, nbrs, out4);
}

// Round 8
// 106.337 us; speedup vs baseline: 2.3287x; 1.9542x over previous
//
#include <hip/hip_runtime.h>

// Problem constants
#define Bz 16      // batch
#define Tin 12     // T_IN
#define Ttot 24    // T_TOTAL
#define NN 5000    // nodes
#define KK 16      // neighbors
#define HH 4       // heads
#define OO 12      // T_TOTAL - T_IN
#define TH 48      // Tin * HH
#define G  8       // bt-groups (2 batches each) == number of XCDs
#define JJ 24      // (b,t) pairs per group

typedef float f32x4 __attribute__((ext_vector_type(4)));
__device__ __forceinline__ void nt_store4(float4* p, float4 v) {
    f32x4 t; t.x = v.x; t.y = v.y; t.z = v.z; t.w = v.w;
    __builtin_nontemporal_store(t, (f32x4*)p);
}

// ============ kernel 1: transpose x -> xT2(g, N, 24), XCD-pinned ============
// bid&7 = g matches the main kernel's mapping, so group g's xT2 slab
// (1.92 MB < 4 MB) stays VALID in XCD g's L2 across the kernel boundary
// (kernel-end release writes back dirty lines but does not invalidate).
#define K1_NB 64

__global__ __launch_bounds__(256) void transpose_kernel(
    const float4* __restrict__ x4, float4* __restrict__ xT2)
{
    __shared__ float4 tile[JJ][K1_NB + 1];
    const int bid = blockIdx.x;
    const int g   = bid & 7;
    const int n0  = (bid >> 3) * K1_NB;
    const int rem = min(K1_NB, NN - n0);
    const int tid = threadIdx.x;
    #pragma unroll
    for (int r = 0; r < (K1_NB * JJ) / 256; r++) {
        int tau = r * 256 + tid;
        int j = tau / K1_NB, i = tau % K1_NB;
        if (i < rem)
            tile[j][i] = x4[(size_t)(g * JJ + j) * NN + n0 + i];
    }
    __syncthreads();
    #pragma unroll
    for (int r = 0; r < (K1_NB * JJ) / 256; r++) {
        int tau = r * 256 + tid;
        int i = tau / JJ, j = tau - i * JJ;
        if (i < rem)
            xT2[((size_t)g * NN + n0 + i) * JJ + j] = tile[j][i];
    }
}

// ====== kernel 2: concat copy + gather + aggregate + GEMM + ReLU ============
#define NPB 8      // nodes per block (5000 = 625 * 8)
#define FST 5      // feat f4-stride per t   (4 heads + 1 pad)
#define FSB 61     // feat f4-stride per b_l (12*5 + 1)
#define FSN 123    // feat f4-stride per nl  (2*61 + 1)

__global__ __launch_bounds__(192) void gnn_main_kernel(
    const float4* __restrict__ x4,    // (BT, N)   -- for the concat copy
    const float4* __restrict__ xT2,   // (G, N, JJ)
    const float* __restrict__ dists,  // (N, K)
    const float* __restrict__ W,      // (48, 12)
    const float* __restrict__ bias,   // (12,)
    const int*   __restrict__ nbrs,   // (N, K)
    float4* __restrict__ out4)        // (B*Ttot, N)
{
    __shared__ float4 feat[NPB * FSN];      // ~15.7 KB
    __shared__ float4 w4_s[NPB][KK];
    __shared__ float  W_s[TH * OO];
    __shared__ float  bias_s[OO];
    __shared__ int    nbr_s[NPB][KK];

    const int bid = blockIdx.x;
    const int g   = bid & 7;                // XCD-pin (locality heuristic only)
    const int n0  = (bid >> 3) * NPB;
    const int tid = threadIdx.x;

    // ---- stage small tensors ----
    for (int i = tid; i < TH * OO; i += 192) W_s[i] = W[i];
    if (tid < OO) bias_s[tid] = bias[tid];
    if (tid < NPB * KK) {
        int nl = tid >> 4, k = tid & 15;
        nbr_s[nl][k] = nbrs[(n0 + nl) * KK + k];
        float d = dists[(n0 + nl) * KK + k];
        float e = -(d * d) * (1.0f / 144.0f);   // h=0 exponent (lam=1/4)
        float4 wv;
        wv.x = expf(e);
        wv.y = expf(2.0f * e);
        wv.z = expf(3.0f * e);
        wv.w = expf(4.0f * e);
        w4_s[nl][k] = wv;
    }

    // ---- concat copy: out[b,t,n0+nl] = x[bt,n0+nl] (L2-hot x slab) ----
    {
        const int j  = tid >> 3;            // 0..23
        const int nl = tid & 7;             // lane-consecutive -> 128 B chunks
        const int bt = g * JJ + j;
        const int b  = bt / Tin, t = bt - b * Tin;
        float4 v = x4[(size_t)bt * NN + n0 + nl];
        nt_store4(&out4[(size_t)(b * Ttot + t) * NN + n0 + nl], v);
    }
    __syncthreads();

    // ---- phase A: gather with 16-deep MLP (all loads in flight) ----
    {
        const int nl  = tid / JJ;            // 0..7
        const int j   = tid - nl * JJ;       // 0..23 (lane-consecutive)
        const int b_l = j / Tin;
        const int t   = j - b_l * Tin;
        const float4* xg = xT2 + (size_t)g * NN * JJ;

        int off[KK];
        #pragma unroll
        for (int k = 0; k < KK; k++)
            off[k] = nbr_s[nl][k] * JJ + j;

        float4 xv[KK];                       // 64 VGPRs of in-flight loads
        #pragma unroll
        for (int k = 0; k < KK; k++)
            xv[k] = xg[off[k]];

        float4 a0 = {0,0,0,0}, a1 = {0,0,0,0}, a2 = {0,0,0,0}, a3 = {0,0,0,0};
        #pragma unroll
        for (int k = 0; k < KK; k++) {
            float4 wv = w4_s[nl][k];
            a0.x += wv.x * xv[k].x; a0.y += wv.x * xv[k].y; a0.z += wv.x * xv[k].z; a0.w += wv.x * xv[k].w;
            a1.x += wv.y * xv[k].x; a1.y += wv.y * xv[k].y; a1.z += wv.y * xv[k].z; a1.w += wv.y * xv[k].w;
            a2.x += wv.z * xv[k].x; a2.y += wv.z * xv[k].y; a2.z += wv.z * xv[k].z; a2.w += wv.z * xv[k].w;
            a3.x += wv.w * xv[k].x; a3.y += wv.w * xv[k].y; a3.z += wv.w * xv[k].z; a3.w += wv.w * xv[k].w;
        }
        const int base = nl * FSN + b_l * FSB + t * FST;
        feat[base + 0] = a0;
        feat[base + 1] = a1;
        feat[base + 2] = a2;
        feat[base + 3] = a3;
    }
    __syncthreads();

    // ---- phase B: (48 -> 12) GEMM + bias + ReLU; full-line nt stores ----
    {
        const int nl  = tid & 7;             // lane-consecutive -> 128 B line
        const int bo  = tid >> 3;            // 0..23
        const int b_l = bo / OO;
        const int o   = bo - b_l * OO;
        const float bz = bias_s[o];
        float4 acc = {bz, bz, bz, bz};
        const int fbase = nl * FSN + b_l * FSB;
        #pragma unroll
        for (int t = 0; t < Tin; t++) {
            #pragma unroll
            for (int h = 0; h < HH; h++) {
                float  wv = W_s[(t * HH + h) * OO + o];
                float4 f  = feat[fbase + t * FST + h];
                acc.x += wv * f.x; acc.y += wv * f.y;
                acc.z += wv * f.z; acc.w += wv * f.w;
            }
        }
        acc.x = fmaxf(acc.x, 0.0f); acc.y = fmaxf(acc.y, 0.0f);
        acc.z = fmaxf(acc.z, 0.0f); acc.w = fmaxf(acc.w, 0.0f);
        const int b = g * 2 + b_l;
        nt_store4(&out4[(size_t)(b * Ttot + Tin + o) * NN + n0 + nl], acc);
    }
}

extern "C" void kernel_launch(void* const* d_in, const int* in_sizes, int n_in,
                              void* d_out, int out_size, void* d_ws, size_t ws_size,
                              hipStream_t stream) {
    const float4* x4    = (const float4*)d_in[0];
    const float*  dists = (const float*)d_in[1];
    const float*  W     = (const float*)d_in[2];
    const float*  bias  = (const float*)d_in[3];
    const int*    nbrs  = (const int*)d_in[4];
    float4* out4 = (float4*)d_out;
    float4* xT2  = (float4*)d_ws;     // G*NN*JJ*16 B = 15.36 MB of ws

    const int ntiles = (NN + K1_NB - 1) / K1_NB;   // 79
    hipLaunchKernelGGL(transpose_kernel, dim3(ntiles * G), dim3(256), 0, stream,
                       x4, xT2);
    hipLaunchKernelGGL(gnn_main_kernel, dim3((NN / NPB) * G), dim3(192), 0, stream,
                       x4, (const float4*)xT2, dists, W, bias, nbrs, out4);
}